// Round 7
// baseline (198.069 us; speedup 1.0000x reference)
//
#include <hip/hip_runtime.h>
#include <math.h>

#define BATCH 256
#define DIN   5120
#define RANK  160
#define NS    16
#define NCAT  192   // RANK + NS + NS
#define NSPLIT 40   // k-splits for k1
#define BQ    8     // batches per k23 block

// ---------------------------------------------------------------------------
// k1a: partial[z] = x(256x5120) @ [W_delta | W_B | W_C] over k-chunk z.
// Split-K (40 chunks of 128), 64x64 tile, 4x4 reg tile. NO atomics:
// each block stores its tile into psum[z][256][192] with plain float4 stores.
// ---------------------------------------------------------------------------
__global__ __launch_bounds__(256) void k1a_gemm(
    const float* __restrict__ x, const float* __restrict__ Wd,
    const float* __restrict__ WB, const float* __restrict__ WC,
    float* __restrict__ psum)
{
    __shared__ float xT[32][64];   // [k][m]
    __shared__ float Wt[32][64];   // [k][n]
    const int t  = threadIdx.x;
    const int m0 = blockIdx.x * 64;
    const int n0 = blockIdx.y * 64;
    const int z  = blockIdx.z;
    const int k0 = z * 128;
    const int tm = (t >> 4) * 4;
    const int tn = (t & 15) * 4;

    const int lm  = t >> 2;
    const int lk  = (t & 3) * 8;
    const int ln  = t & 63;
    const int lkb = (t >> 6) * 8;

    const float* wsrc; int wstr;
    {
        const int c = n0 + ln;
        if (c < RANK)            { wsrc = Wd + c;                wstr = RANK; }
        else if (c < RANK + NS)  { wsrc = WB + (c - RANK);       wstr = NS;   }
        else                     { wsrc = WC + (c - RANK - NS);  wstr = NS;   }
    }

    float acc[4][4] = {{0.f}};

    for (int ks = 0; ks < 4; ++ks) {
        const int kb = k0 + ks * 32;
        {
            const float* src = x + (size_t)(m0 + lm) * DIN + kb + lk;
            const float4 a0 = *(const float4*)src;
            const float4 a1 = *(const float4*)(src + 4);
            xT[lk+0][lm]=a0.x; xT[lk+1][lm]=a0.y; xT[lk+2][lm]=a0.z; xT[lk+3][lm]=a0.w;
            xT[lk+4][lm]=a1.x; xT[lk+5][lm]=a1.y; xT[lk+6][lm]=a1.z; xT[lk+7][lm]=a1.w;
        }
        {
            const float* wp = wsrc + (size_t)(kb + lkb) * wstr;
            #pragma unroll
            for (int i = 0; i < 8; ++i) { Wt[lkb + i][ln] = *wp; wp += wstr; }
        }
        __syncthreads();
        #pragma unroll
        for (int k = 0; k < 32; ++k) {
            const float4 a = *(const float4*)&xT[k][tm];
            const float4 b = *(const float4*)&Wt[k][tn];
            acc[0][0] += a.x*b.x; acc[0][1] += a.x*b.y; acc[0][2] += a.x*b.z; acc[0][3] += a.x*b.w;
            acc[1][0] += a.y*b.x; acc[1][1] += a.y*b.y; acc[1][2] += a.y*b.z; acc[1][3] += a.y*b.w;
            acc[2][0] += a.z*b.x; acc[2][1] += a.z*b.y; acc[2][2] += a.z*b.z; acc[2][3] += a.z*b.w;
            acc[3][0] += a.w*b.x; acc[3][1] += a.w*b.y; acc[3][2] += a.w*b.z; acc[3][3] += a.w*b.w;
        }
        __syncthreads();
    }

    float* dst = psum + (size_t)z * (BATCH * NCAT);
    #pragma unroll
    for (int i = 0; i < 4; ++i) {
        const int gm = m0 + tm + i;
        float4 o; o.x = acc[i][0]; o.y = acc[i][1]; o.z = acc[i][2]; o.w = acc[i][3];
        *(float4*)&dst[(size_t)gm * NCAT + n0 + tn] = o;
    }
}

// ---------------------------------------------------------------------------
// k1r: (blocks 0..191) reduce 40 psum partials -> P/Bp/Cc;
//      (all 320 blocks) A2 = -log2(e)*exp(A_log), 81920 elements.
// ---------------------------------------------------------------------------
__global__ __launch_bounds__(256) void k1r_reduce(
    const float* __restrict__ psum, const float* __restrict__ A_log,
    float* __restrict__ P, float* __restrict__ Bp, float* __restrict__ Cc,
    float* __restrict__ A2t)
{
    const int g = blockIdx.x * 256 + threadIdx.x;     // 0..81919
    A2t[g] = -1.442695041f * __expf(A_log[g]);

    if (blockIdx.x < NCAT) {
        const int o = blockIdx.x * 256 + threadIdx.x; // 0..49151
        float s = 0.f;
        #pragma unroll 8
        for (int z = 0; z < NSPLIT; ++z) s += psum[(size_t)z * (BATCH * NCAT) + o];
        const int gm = o / NCAT;
        const int gc = o - gm * NCAT;
        if (gc < RANK)           P [gm * RANK + gc]             = s;
        else if (gc < RANK + NS) Bp[gm * NS   + gc - RANK]      = s;
        else                     Cc[gm * NS   + gc - RANK - NS] = s;
    }
}

__device__ __forceinline__ float softplus20(float z)
{
    if (z > 20.f) return z;
    return fmaxf(z, 0.f) + log1pf(__expf(-fabsf(z)));
}

// ---------------------------------------------------------------------------
// k23: fused dt-GEMM + SSM update + readout. Block = 8 batches x 256 channels,
// grid 640. dt-phase: thread t <-> channel c0+t; P[b][k] accessed with
// wave-uniform indices from global (scalar-load path, no LDS issue cost);
// Wdt columns coalesced (L2-resident). dt crosses to the SSM lane-layout via
// an 8KB LDS tile + one block-local __syncthreads.
// SSM phase: fully-coalesced h/A2 reads (1KB per wave-instruction),
// 4-lane shfl_xor finishes the n-sum.
// ---------------------------------------------------------------------------
__global__ __launch_bounds__(256) void k23_ssm(
    const float* __restrict__ P, const float* __restrict__ Wdt,
    const float* __restrict__ bdt, const float* __restrict__ x,
    const float* __restrict__ h, const float* __restrict__ A2t,
    const float* __restrict__ Bp, const float* __restrict__ Cc,
    const float* __restrict__ Dv, float* __restrict__ y)
{
    __shared__ float sdt[BQ][256];

    const int t  = threadIdx.x;
    const int ct = blockIdx.x % 20;
    const int bg = blockIdx.x / 20;
    const int c0 = ct * 256;
    const int b0 = bg * BQ;

    // ---- phase A: dt for this block's channels, 8 batches ----
    {
        const int c = c0 + t;
        float acc[BQ];
        #pragma unroll
        for (int b = 0; b < BQ; ++b) acc[b] = 0.f;
        const float* wcol = Wdt + c;
        const float* Pb   = P + (size_t)b0 * RANK;
        #pragma unroll 4
        for (int k = 0; k < RANK; ++k) {
            const float w = wcol[(size_t)k * DIN];
            #pragma unroll
            for (int b = 0; b < BQ; ++b) acc[b] += Pb[b * RANK + k] * w;
        }
        const float bb = bdt[c];
        #pragma unroll
        for (int b = 0; b < BQ; ++b) sdt[b][t] = softplus20(acc[b] + bb);
    }
    __syncthreads();

    // ---- phase B: SSM update + readout ----
    const int lane = t & 63;
    const int wv   = t >> 6;
    const int v    = lane & 3;    // state quad: n = 4v..4v+3
    const int j    = lane >> 2;   // channel within 16
    const int cb   = c0 + wv * 64;

    float4 A2q[4];
    #pragma unroll
    for (int q = 0; q < 4; ++q)
        A2q[q] = *(const float4*)(A2t + (size_t)(cb + q * 16 + j) * NS + v * 4);

    #pragma unroll 2
    for (int b = 0; b < BQ; ++b) {
        const int gb = b0 + b;
        const float4 B4 = *(const float4*)(Bp + gb * NS + v * 4);
        const float4 C4 = *(const float4*)(Cc + gb * NS + v * 4);
        float res[4];
        #pragma unroll
        for (int q = 0; q < 4; ++q) {
            const int cq  = cb + q * 16 + j;
            const float dtv = sdt[b][wv * 64 + q * 16 + j];
            const float xv  = x[(size_t)gb * DIN + cq];
            const float dtx = dtv * xv;
            const float4 h4 = *(const float4*)(h + ((size_t)gb * DIN + cq) * NS + v * 4);
            float s;
            s  = (exp2f(dtv * A2q[q].x) * h4.x + dtx * B4.x) * C4.x;
            s += (exp2f(dtv * A2q[q].y) * h4.y + dtx * B4.y) * C4.y;
            s += (exp2f(dtv * A2q[q].z) * h4.z + dtx * B4.z) * C4.z;
            s += (exp2f(dtv * A2q[q].w) * h4.w + dtx * B4.w) * C4.w;
            if (v == 0) s += xv * Dv[cq];
            res[q] = s;
        }
        #pragma unroll
        for (int q = 0; q < 4; ++q) {
            res[q] += __shfl_xor(res[q], 1, 64);
            res[q] += __shfl_xor(res[q], 2, 64);
        }
        if (v == 0) {
            #pragma unroll
            for (int q = 0; q < 4; ++q)
                y[(size_t)gb * DIN + cb + q * 16 + j] = res[q];
        }
    }
}

// ---------------------------------------------------------------------------
extern "C" void kernel_launch(void* const* d_in, const int* in_sizes, int n_in,
                              void* d_out, int out_size, void* d_ws, size_t ws_size,
                              hipStream_t stream)
{
    const float* x     = (const float*)d_in[0];
    const float* h     = (const float*)d_in[1];
    const float* Wd    = (const float*)d_in[2];
    const float* Wdt   = (const float*)d_in[3];
    const float* bdt   = (const float*)d_in[4];
    const float* A_log = (const float*)d_in[5];
    const float* WB    = (const float*)d_in[6];
    const float* WC    = (const float*)d_in[7];
    const float* Dv    = (const float*)d_in[8];
    float* out = (float*)d_out;

    // ws layout (floats): psum (40x256x192) | P | Bp | Cc | A2 (5120x16)
    float* psum = (float*)d_ws;
    float* P    = psum + (size_t)NSPLIT * BATCH * NCAT;
    float* Bp   = P  + BATCH * RANK;
    float* Cc   = Bp + BATCH * NS;
    float* A2t  = Cc + BATCH * NS;

    // no memset needed: every ws word is written before it is read
    k1a_gemm  <<<dim3(4, 3, NSPLIT),   256, 0, stream>>>(x, Wd, WB, WC, psum);
    k1r_reduce<<<dim3(320),            256, 0, stream>>>(psum, A_log, P, Bp, Cc, A2t);
    k23_ssm   <<<dim3(20 * BATCH/BQ),  256, 0, stream>>>(P, Wdt, bdt, x, h, A2t, Bp, Cc, Dv, out);
}

// Round 8
// 181.865 us; speedup vs baseline: 1.0891x; 1.0891x over previous
//
#include <hip/hip_runtime.h>
#include <math.h>

#define BATCH 256
#define DIN   5120
#define RANK  160
#define NS    16
#define NCAT  192   // RANK + NS + NS
#define NSPLIT 40   // k-splits for k1

// ---------------------------------------------------------------------------
// k1a: partial[z] = x(256x5120) @ [W_delta | W_B | W_C] over k-chunk z.
// Split-K (40 chunks of 128), 64x64 tile, 4x4 reg tile. NO atomics.
// ---------------------------------------------------------------------------
__global__ __launch_bounds__(256) void k1a_gemm(
    const float* __restrict__ x, const float* __restrict__ Wd,
    const float* __restrict__ WB, const float* __restrict__ WC,
    float* __restrict__ psum)
{
    __shared__ float xT[32][64];   // [k][m]
    __shared__ float Wt[32][64];   // [k][n]
    const int t  = threadIdx.x;
    const int m0 = blockIdx.x * 64;
    const int n0 = blockIdx.y * 64;
    const int z  = blockIdx.z;
    const int k0 = z * 128;
    const int tm = (t >> 4) * 4;
    const int tn = (t & 15) * 4;

    const int lm  = t >> 2;
    const int lk  = (t & 3) * 8;
    const int ln  = t & 63;
    const int lkb = (t >> 6) * 8;

    const float* wsrc; int wstr;
    {
        const int c = n0 + ln;
        if (c < RANK)            { wsrc = Wd + c;                wstr = RANK; }
        else if (c < RANK + NS)  { wsrc = WB + (c - RANK);       wstr = NS;   }
        else                     { wsrc = WC + (c - RANK - NS);  wstr = NS;   }
    }

    float acc[4][4] = {{0.f}};

    for (int ks = 0; ks < 4; ++ks) {
        const int kb = k0 + ks * 32;
        {
            const float* src = x + (size_t)(m0 + lm) * DIN + kb + lk;
            const float4 a0 = *(const float4*)src;
            const float4 a1 = *(const float4*)(src + 4);
            xT[lk+0][lm]=a0.x; xT[lk+1][lm]=a0.y; xT[lk+2][lm]=a0.z; xT[lk+3][lm]=a0.w;
            xT[lk+4][lm]=a1.x; xT[lk+5][lm]=a1.y; xT[lk+6][lm]=a1.z; xT[lk+7][lm]=a1.w;
        }
        {
            const float* wp = wsrc + (size_t)(kb + lkb) * wstr;
            #pragma unroll
            for (int i = 0; i < 8; ++i) { Wt[lkb + i][ln] = *wp; wp += wstr; }
        }
        __syncthreads();
        #pragma unroll
        for (int k = 0; k < 32; ++k) {
            const float4 a = *(const float4*)&xT[k][tm];
            const float4 b = *(const float4*)&Wt[k][tn];
            acc[0][0] += a.x*b.x; acc[0][1] += a.x*b.y; acc[0][2] += a.x*b.z; acc[0][3] += a.x*b.w;
            acc[1][0] += a.y*b.x; acc[1][1] += a.y*b.y; acc[1][2] += a.y*b.z; acc[1][3] += a.y*b.w;
            acc[2][0] += a.z*b.x; acc[2][1] += a.z*b.y; acc[2][2] += a.z*b.z; acc[2][3] += a.z*b.w;
            acc[3][0] += a.w*b.x; acc[3][1] += a.w*b.y; acc[3][2] += a.w*b.z; acc[3][3] += a.w*b.w;
        }
        __syncthreads();
    }

    float* dst = psum + (size_t)z * (BATCH * NCAT);
    #pragma unroll
    for (int i = 0; i < 4; ++i) {
        const int gm = m0 + tm + i;
        float4 o; o.x = acc[i][0]; o.y = acc[i][1]; o.z = acc[i][2]; o.w = acc[i][3];
        *(float4*)&dst[(size_t)gm * NCAT + n0 + tn] = o;
    }
}

// ---------------------------------------------------------------------------
// k1r: (blocks 0..191) reduce 40 psum partials -> P/Bp/Cc;
//      (all 320 blocks) A2 = -log2(e)*exp(A_log), 81920 elements.
// ---------------------------------------------------------------------------
__global__ __launch_bounds__(256) void k1r_reduce(
    const float* __restrict__ psum, const float* __restrict__ A_log,
    float* __restrict__ P, float* __restrict__ Bp, float* __restrict__ Cc,
    float* __restrict__ A2t)
{
    const int g = blockIdx.x * 256 + threadIdx.x;     // 0..81919
    A2t[g] = -1.442695041f * __expf(A_log[g]);

    if (blockIdx.x < NCAT) {
        const int o = blockIdx.x * 256 + threadIdx.x; // 0..49151
        float s = 0.f;
        #pragma unroll 8
        for (int z = 0; z < NSPLIT; ++z) s += psum[(size_t)z * (BATCH * NCAT) + o];
        const int gm = o / NCAT;
        const int gc = o - gm * NCAT;
        if (gc < RANK)           P [gm * RANK + gc]             = s;
        else if (gc < RANK + NS) Bp[gm * NS   + gc - RANK]      = s;
        else                     Cc[gm * NS   + gc - RANK - NS] = s;
    }
}

__device__ __forceinline__ float softplus20(float z)
{
    if (z > 20.f) return z;
    return fmaxf(z, 0.f) + log1pf(__expf(-fabsf(z)));
}

// ---------------------------------------------------------------------------
// k23: fused dt-GEMM + SSM, block = 64 batches x 64 channels, grid (80,4).
// Phase A: R4-k2a LDS-tiled GEMM (K=160), softplus epilogue -> sdt[64][64] LDS.
// Phase B: R6-k3 coalesced SSM: wave wv handles batches b0+wv*16..+15;
// lane 4j+v covers channel c0+q*16+j, states 4v..4v+3; every h wave-load is
// 1 KB contiguous; 4-lane shfl_xor finishes the n-sum. dt comes from LDS.
// ---------------------------------------------------------------------------
__global__ __launch_bounds__(256) void k23_ssm(
    const float* __restrict__ P, const float* __restrict__ Wdt,
    const float* __restrict__ bdt, const float* __restrict__ x,
    const float* __restrict__ h, const float* __restrict__ A2t,
    const float* __restrict__ Bp, const float* __restrict__ Cc,
    const float* __restrict__ Dv, float* __restrict__ y)
{
    __shared__ float aT[32][64];    // [k][m] P tile
    __shared__ float Bt[32][64];    // [k][n] Wdt tile
    __shared__ float sdt[64][64];   // [b_local][c_local]

    const int t  = threadIdx.x;
    const int c0 = blockIdx.x * 64;   // 80 channel tiles
    const int b0 = blockIdx.y * 64;   // 4 batch tiles

    // ---- phase A: dt tile GEMM (M=64 batches, N=64 channels, K=160) ----
    {
        const int tm = (t >> 4) * 4;
        const int tn = (t & 15) * 4;
        const int lm  = t >> 2;
        const int lk  = (t & 3) * 8;
        const int ln  = t & 63;
        const int lkb = (t >> 6) * 8;

        float acc[4][4] = {{0.f}};

        for (int ks = 0; ks < 5; ++ks) {
            const int kb = ks * 32;
            {
                const float* src = P + (size_t)(b0 + lm) * RANK + kb + lk;
                const float4 a0 = *(const float4*)src;
                const float4 a1 = *(const float4*)(src + 4);
                aT[lk+0][lm]=a0.x; aT[lk+1][lm]=a0.y; aT[lk+2][lm]=a0.z; aT[lk+3][lm]=a0.w;
                aT[lk+4][lm]=a1.x; aT[lk+5][lm]=a1.y; aT[lk+6][lm]=a1.z; aT[lk+7][lm]=a1.w;
            }
            {
                const float* wp = Wdt + (size_t)(kb + lkb) * DIN + c0 + ln;
                #pragma unroll
                for (int i = 0; i < 8; ++i) { Bt[lkb + i][ln] = wp[(size_t)i * DIN]; }
            }
            __syncthreads();
            #pragma unroll
            for (int k = 0; k < 32; ++k) {
                const float4 a = *(const float4*)&aT[k][tm];
                const float4 b = *(const float4*)&Bt[k][tn];
                acc[0][0] += a.x*b.x; acc[0][1] += a.x*b.y; acc[0][2] += a.x*b.z; acc[0][3] += a.x*b.w;
                acc[1][0] += a.y*b.x; acc[1][1] += a.y*b.y; acc[1][2] += a.y*b.z; acc[1][3] += a.y*b.w;
                acc[2][0] += a.z*b.x; acc[2][1] += a.z*b.y; acc[2][2] += a.z*b.z; acc[2][3] += a.z*b.w;
                acc[3][0] += a.w*b.x; acc[3][1] += a.w*b.y; acc[3][2] += a.w*b.z; acc[3][3] += a.w*b.w;
            }
            __syncthreads();
        }

        const float4 bz = *(const float4*)&bdt[c0 + tn];
        #pragma unroll
        for (int i = 0; i < 4; ++i) {
            float4 o;
            o.x = softplus20(acc[i][0] + bz.x);
            o.y = softplus20(acc[i][1] + bz.y);
            o.z = softplus20(acc[i][2] + bz.z);
            o.w = softplus20(acc[i][3] + bz.w);
            *(float4*)&sdt[tm + i][tn] = o;
        }
    }
    __syncthreads();

    // ---- phase B: SSM update + readout for this 64b x 64c slice ----
    const int lane = t & 63;
    const int wv   = t >> 6;       // wave -> batches b0 + wv*16 .. +15
    const int v    = lane & 3;     // state quad: n = 4v..4v+3
    const int j    = lane >> 2;    // channel within 16

    float4 A2q[4]; float dvq[4];
    #pragma unroll
    for (int q = 0; q < 4; ++q) {
        const int c = c0 + q * 16 + j;
        A2q[q] = *(const float4*)(A2t + (size_t)c * NS + v * 4);
        dvq[q] = Dv[c];
    }

    #pragma unroll 4
    for (int bi = 0; bi < 16; ++bi) {
        const int bl = wv * 16 + bi;
        const int gb = b0 + bl;
        const float4 B4 = *(const float4*)(Bp + gb * NS + v * 4);
        const float4 C4 = *(const float4*)(Cc + gb * NS + v * 4);
        float res[4];
        #pragma unroll
        for (int q = 0; q < 4; ++q) {
            const int c = c0 + q * 16 + j;
            const float dtv = sdt[bl][q * 16 + j];
            const float xv  = x[(size_t)gb * DIN + c];
            const float dtx = dtv * xv;
            const float4 h4 = *(const float4*)(h + ((size_t)gb * DIN + c) * NS + v * 4);
            float s;
            s  = (exp2f(dtv * A2q[q].x) * h4.x + dtx * B4.x) * C4.x;
            s += (exp2f(dtv * A2q[q].y) * h4.y + dtx * B4.y) * C4.y;
            s += (exp2f(dtv * A2q[q].z) * h4.z + dtx * B4.z) * C4.z;
            s += (exp2f(dtv * A2q[q].w) * h4.w + dtx * B4.w) * C4.w;
            if (v == 0) s += xv * dvq[q];
            res[q] = s;
        }
        #pragma unroll
        for (int q = 0; q < 4; ++q) {
            res[q] += __shfl_xor(res[q], 1, 64);
            res[q] += __shfl_xor(res[q], 2, 64);
        }
        if (v == 0) {
            #pragma unroll
            for (int q = 0; q < 4; ++q)
                y[(size_t)gb * DIN + c0 + q * 16 + j] = res[q];
        }
    }
}

// ---------------------------------------------------------------------------
extern "C" void kernel_launch(void* const* d_in, const int* in_sizes, int n_in,
                              void* d_out, int out_size, void* d_ws, size_t ws_size,
                              hipStream_t stream)
{
    const float* x     = (const float*)d_in[0];
    const float* h     = (const float*)d_in[1];
    const float* Wd    = (const float*)d_in[2];
    const float* Wdt   = (const float*)d_in[3];
    const float* bdt   = (const float*)d_in[4];
    const float* A_log = (const float*)d_in[5];
    const float* WB    = (const float*)d_in[6];
    const float* WC    = (const float*)d_in[7];
    const float* Dv    = (const float*)d_in[8];
    float* out = (float*)d_out;

    // ws layout (floats): psum (40x256x192) | P | Bp | Cc | A2 (5120x16)
    float* psum = (float*)d_ws;
    float* P    = psum + (size_t)NSPLIT * BATCH * NCAT;
    float* Bp   = P  + BATCH * RANK;
    float* Cc   = Bp + BATCH * NS;
    float* A2t  = Cc + BATCH * NS;

    // no memset needed: every ws word is written before it is read
    k1a_gemm  <<<dim3(4, 3, NSPLIT), 256, 0, stream>>>(x, Wd, WB, WC, psum);
    k1r_reduce<<<dim3(320),          256, 0, stream>>>(psum, A_log, P, Bp, Cc, A2t);
    k23_ssm   <<<dim3(80, 4),        256, 0, stream>>>(P, Wdt, bdt, x, h, A2t, Bp, Cc, Dv, out);
}